// Round 26
// baseline (26.202 us; speedup 1.0000x reference)
//
#include <hip/hip_runtime.h>

// MarkovTransition: x (4, 8192, 8) fp32 -> P (4, 8, 128, 128) fp32.
// VERIFIED SEMANTICS (r23/r24, absmax 0.0): per-series (b,f) min/max;
// inv = RN(1/max(mx-mn,1e-8)); xn = (v-mn)*inv; s = xn*127; clip; floor.
// C[s,t] counts consecutive-pair transitions; P = C / max(rowsum, 1e-8).
//
// r26: r25's 3-kernel split with the K2 reduce bug FIXED. r25 reduced
// partial min/max over global chunks 0..127 = ALL FOUR batches (chunk id
// g=(b<<5)|p), normalizing each series by the cross-b min/max -> bucket
// 127 emptied -> absmax exactly 1.0. Now each series reduces only its own
// batch's 32 chunks: t<64, f=t&7, q=t>>3 merges chunks b*32+q*4+{0..3}
// serially then shfl_xor 8/16/32 across q -> exact per-(b,f) min/max,
// bit-identical to r24's verified reduction.

__device__ __forceinline__ float ieee_div_rn(float a, float d) {
    // Correctly-rounded (RNE) fp32 a/d for finite a >= 0, d > 0.
    // Pure integer arithmetic -> immune to any compiler math flags.
    if (a == 0.0f) return 0.0f;
    unsigned ua = __float_as_uint(a), ud = __float_as_uint(d);
    int      Ea = (int)((ua >> 23) & 0xFFu);
    int      Ed = (int)((ud >> 23) & 0xFFu);
    unsigned Ma = ua & 0x7FFFFFu;
    unsigned Md = ud & 0x7FFFFFu;
    if (Ea) { Ma |= 0x800000u; } else { int sh = __clz(Ma) - 8; Ma <<= sh; Ea = 1 - sh; }
    if (Ed) { Md |= 0x800000u; } else { int sh = __clz(Md) - 8; Md <<= sh; Ed = 1 - sh; }
    unsigned long long num = (unsigned long long)Ma << 26;
    unsigned long long q0  = num / Md;
    unsigned long long rem = num - q0 * Md;
    unsigned Q, rnd; bool sticky; int Eout;
    if (q0 >= (1ull << 26)) {
        Q = (unsigned)(q0 >> 3); rnd = (unsigned)(q0 >> 2) & 1u;
        sticky = ((q0 & 3ull) != 0) || (rem != 0); Eout = Ea - Ed + 127;
    } else {
        Q = (unsigned)(q0 >> 2); rnd = (unsigned)(q0 >> 1) & 1u;
        sticky = ((q0 & 1ull) != 0) || (rem != 0); Eout = Ea - Ed + 126;
    }
    if (rnd && (sticky || (Q & 1u))) ++Q;
    if (Q == (1u << 24)) { Q = 1u << 23; ++Eout; }
    if (Eout < 1)   return 0.0f;
    if (Eout > 254) Eout = 254;
    return __uint_as_float(((unsigned)Eout << 23) | (Q & 0x7FFFFFu));
}

__device__ __forceinline__ int np_bucket(float v, float mn, float inv) {
    float a  = v - mn;              // single IEEE sub
    float xn = a * inv;             // single IEEE mul (RN)
    asm volatile("" : "+v"(xn));    // forbid (a*inv)*127 reassociation
    float s  = xn * 127.0f;         // single IEEE mul (RN)
    s = fminf(fmaxf(s, 0.0f), 127.0f);
    return (int)s;                  // trunc == floor (s >= 0)
}

// K1: coalesced per-f partial min/max (chunk g=(b<<5)|p, feature f) + zero
// counts. grid 128, block 256. Thread t: row l = p*256+t, 8 contiguous floats.
extern "C" __global__ __launch_bounds__(256)
void mt_k1(const float* __restrict__ x, float* __restrict__ mnp,
           float* __restrict__ mxp, unsigned int* __restrict__ cnt)
{
    __shared__ float smn[4][8], smx[4][8];
    const int g = blockIdx.x, b = g >> 5, p = g & 31;
    const int t = threadIdx.x;
    const float* base = x + b * 65536 + (p * 256 + t) * 8;

    float mn[8], mx[8];
    #pragma unroll
    for (int k = 0; k < 8; ++k) { float v = base[k]; mn[k] = v; mx[k] = v; }

    // zero this block's 16KB slice of the count buffer (poison-safe)
    unsigned int* cz = cnt + g * 4096;
    #pragma unroll
    for (int i = 0; i < 16; ++i) cz[t + i * 256] = 0u;

    #pragma unroll
    for (int off = 32; off > 0; off >>= 1) {
        #pragma unroll
        for (int k = 0; k < 8; ++k) {
            mn[k] = fminf(mn[k], __shfl_xor(mn[k], off));
            mx[k] = fmaxf(mx[k], __shfl_xor(mx[k], off));
        }
    }
    const int wave = t >> 6, lane = t & 63;
    if (lane == 0) {
        #pragma unroll
        for (int k = 0; k < 8; ++k) { smn[wave][k] = mn[k]; smx[wave][k] = mx[k]; }
    }
    __syncthreads();
    if (t < 8) {
        float a = smn[0][t], c = smx[0][t];
        #pragma unroll
        for (int w = 1; w < 4; ++w) { a = fminf(a, smn[w][t]); c = fmaxf(c, smx[w][t]); }
        mnp[g * 8 + t] = a;
        mxp[g * 8 + t] = c;
    }
}

// K2: buckets + global-atomic transition histogram. grid 128 = (b<<5)|p.
extern "C" __global__ __launch_bounds__(256)
void mt_k2(const float* __restrict__ x, const float* __restrict__ mnp,
           const float* __restrict__ mxp, unsigned int* __restrict__ cnt)
{
    __shared__ float s_mn[8], s_inv[8];
    __shared__ unsigned char bkl[256 * 8];
    const int g = blockIdx.x, b = g >> 5, p = g & 31;
    const int t = threadIdx.x;
    const int l = p * 256 + t;

    // FIXED reduce: only batch b's 32 chunks (global chunk id b*32+p).
    // t<64: f = t&7, q = t>>3; 4 chunks serial, then merge q^1, q^2, q^4.
    if (t < 64) {
        const int f = t & 7, q = t >> 3;
        const int g0 = b * 32 + q * 4;
        float a = mnp[g0 * 8 + f], c = mxp[g0 * 8 + f];
        #pragma unroll
        for (int i = 1; i < 4; ++i) {
            a = fminf(a, mnp[(g0 + i) * 8 + f]);
            c = fmaxf(c, mxp[(g0 + i) * 8 + f]);
        }
        a = fminf(a, __shfl_xor(a, 8));  c = fmaxf(c, __shfl_xor(c, 8));
        a = fminf(a, __shfl_xor(a, 16)); c = fmaxf(c, __shfl_xor(c, 16));
        a = fminf(a, __shfl_xor(a, 32)); c = fmaxf(c, __shfl_xor(c, 32));
        if (t < 8) {
            s_mn[t]  = a;
            s_inv[t] = ieee_div_rn(1.0f, fmaxf(c - a, 1e-8f));  // exact RN
        }
    }
    __syncthreads();

    const float* base = x + b * 65536 + l * 8;
    int bk[8];
    #pragma unroll
    for (int k = 0; k < 8; ++k) {
        bk[k] = np_bucket(base[k], s_mn[k], s_inv[k]);
        bkl[t * 8 + k] = (unsigned char)bk[k];
    }
    __syncthreads();

    if (t < 255) {                       // successor = thread t+1, same chunk
        #pragma unroll
        for (int k = 0; k < 8; ++k) {
            const int nb = (int)bkl[(t + 1) * 8 + k];
            atomicAdd(&cnt[(b * 8 + k) * 16384 + bk[k] * 128 + nb], 1u);
        }
    } else if (l < 8191) {               // chunk edge: reload successor row
        const float* nx = x + b * 65536 + (l + 1) * 8;
        #pragma unroll
        for (int k = 0; k < 8; ++k) {
            const int nb = np_bucket(nx[k], s_mn[k], s_inv[k]);
            atomicAdd(&cnt[(b * 8 + k) * 16384 + bk[k] * 128 + nb], 1u);
        }
    }
}

// K3: rowsum + normalize + coalesced store. grid 256 = (s<<3)|rg, block 256.
extern "C" __global__ __launch_bounds__(256)
void mt_k3(const unsigned int* __restrict__ cnt, float* __restrict__ out)
{
    const int g = blockIdx.x, s = g >> 3, rg = g & 7;
    const int t = threadIdx.x;
    const int row = rg * 16 + (t >> 4);      // 16 rows/block, 16 threads/row
    const int j = t & 15;
    const unsigned int* c = cnt + s * 16384 + row * 128 + j * 8;
    unsigned int u[8]; unsigned sum = 0;
    #pragma unroll
    for (int i = 0; i < 8; ++i) { u[i] = c[i]; sum += u[i]; }
    sum += __shfl_xor(sum, 1);
    sum += __shfl_xor(sum, 2);
    sum += __shfl_xor(sum, 4);
    sum += __shfl_xor(sum, 8);               // 16-lane group = one row
    const float rs = fmaxf((float)sum, 1e-8f);
    float* o = out + s * 16384 + row * 128 + j * 8;
    #pragma unroll
    for (int i = 0; i < 8; ++i) o[i] = (float)u[i] / rs;
}

// Fallback: r24 monolithic kernel (verified absmax 0.0), used if ws too small.
extern "C" __global__ __launch_bounds__(1024)
void MarkovTransition_50637664420500_kernel(const float* __restrict__ x,
                                            float* __restrict__ out)
{
    __shared__ unsigned int  cp[8192];
    __shared__ unsigned char bk0[1024];
    __shared__ float         rs[128];
    const int tid = threadIdx.x, bid = blockIdx.x;
    const float* xs = x + (bid >> 3) * 65536 + (bid & 7);
    float v[8];
    const int lbase = tid * 8;
    #pragma unroll
    for (int k = 0; k < 8; ++k) v[k] = xs[(lbase + k) * 8];
    float mn = v[0], mx = v[0];
    #pragma unroll
    for (int k = 1; k < 8; ++k) { mn = fminf(mn, v[k]); mx = fmaxf(mx, v[k]); }
    #pragma unroll
    for (int off = 32; off > 0; off >>= 1) {
        mn = fminf(mn, __shfl_xor(mn, off));
        mx = fmaxf(mx, __shfl_xor(mx, off));
    }
    const int wid = tid >> 6, lane = tid & 63;
    if (lane == 0) { cp[wid] = __float_as_uint(mn); cp[64 + wid] = __float_as_uint(mx); }
    __syncthreads();
    if (tid == 0) {
        float m0 = __uint_as_float(cp[0]), m1 = __uint_as_float(cp[64]);
        for (int t2 = 1; t2 < 16; ++t2) {
            m0 = fminf(m0, __uint_as_float(cp[t2]));
            m1 = fmaxf(m1, __uint_as_float(cp[64 + t2]));
        }
        cp[128] = __float_as_uint(m0); cp[129] = __float_as_uint(m1);
    }
    __syncthreads();
    const float x_min = __uint_as_float(cp[128]);
    const float inv   = ieee_div_rn(1.0f, fmaxf(__uint_as_float(cp[129]) - x_min, 1e-8f));
    __syncthreads();
    int bk[8];
    #pragma unroll
    for (int k = 0; k < 8; ++k) bk[k] = np_bucket(v[k], x_min, inv);
    bk0[tid] = (unsigned char)bk[0];
    #pragma unroll
    for (int i = 0; i < 8; ++i) cp[tid + i * 1024] = 0u;
    __syncthreads();
    #pragma unroll
    for (int k = 0; k < 7; ++k) {
        const int cell = bk[k] * 128 + bk[k + 1];
        atomicAdd(&cp[cell >> 1], 1u << ((cell & 1) << 4));
    }
    if (tid < 1023) {
        const int cell = bk[7] * 128 + (int)bk0[tid + 1];
        atomicAdd(&cp[cell >> 1], 1u << ((cell & 1) << 4));
    }
    __syncthreads();
    {
        const int j = tid & 7;
        unsigned s = 0;
        #pragma unroll
        for (int i = 0; i < 8; ++i) {
            const unsigned u = cp[tid * 8 + i];
            s += (u & 0xFFFFu) + (u >> 16);
        }
        s += __shfl_xor(s, 1); s += __shfl_xor(s, 2); s += __shfl_xor(s, 4);
        if (j == 0) rs[tid >> 3] = fmaxf((float)s, 1e-8f);
    }
    __syncthreads();
    float2* P2 = (float2*)(out + bid * 16384);
    #pragma unroll
    for (int i = 0; i < 8; ++i) {
        const int w = tid + i * 1024;
        const unsigned u = cp[w];
        const float r = rs[w >> 6];
        P2[w] = make_float2((float)(u & 0xFFFFu) / r, (float)(u >> 16) / r);
    }
}

extern "C" void kernel_launch(void* const* d_in, const int* in_sizes, int n_in,
                              void* d_out, int out_size, void* d_ws, size_t ws_size,
                              hipStream_t stream) {
    const float* x = (const float*)d_in[0];
    float* out = (float*)d_out;
    const size_t need = 8192 + (size_t)524288 * 4;   // partials + 2MB counts
    if (ws_size >= need) {
        float* mnp = (float*)d_ws;                        // 128*8 floats
        float* mxp = mnp + 1024;                          // 128*8 floats
        unsigned int* cnt = (unsigned int*)((char*)d_ws + 8192);
        mt_k1<<<128, 256, 0, stream>>>(x, mnp, mxp, cnt);
        mt_k2<<<128, 256, 0, stream>>>(x, mnp, mxp, cnt);
        mt_k3<<<256, 256, 0, stream>>>(cnt, out);
    } else {
        MarkovTransition_50637664420500_kernel<<<32, 1024, 0, stream>>>(x, out);
    }
}

// Round 27
// 14.410 us; speedup vs baseline: 1.8183x; 1.8183x over previous
//
#include <hip/hip_runtime.h>

// MarkovTransition: x (4, 8192, 8) fp32 -> P (4, 8, 128, 128) fp32.
// VERIFIED SEMANTICS (r23/r24/r26, absmax 0.0): per-series (b,f) min/max;
// inv = RN(1/max(mx-mn,1e-8)); xn = (v-mn)*inv; s = xn*127; clip; floor.
// C[s,t] counts consecutive-pair transitions; P = C / max(rowsum, 1e-8).
//
// r27: single kernel (r26 proved each extra graph node costs ~4-6 us —
// 3-kernel split was 26 us vs monolithic 14 us). vs r24:
//  - wave-coalesced mapping l = w*512 + k*64 + lane: each wave-load spans
//    2KB contiguous (32 lines, 2 lanes/line) instead of 16KB scatter
//    (64 lines) -> half the vmem transactions; successors via shfl_down.
//  - XCD-pair block swizzle bid = b + 4*f: the 8 blocks sharing batch b sit
//    on 2 XCD residues instead of 8 -> FETCH ~8x -> ~2x input size.
//  - parallel minmax merge, float4 stores.
// Bucket chain byte-identical -> output bit-identical (absmax 0.0).

__device__ __forceinline__ float ieee_div_rn(float a, float d) {
    // Correctly-rounded (RNE) fp32 a/d for finite a >= 0, d > 0.
    // Pure integer arithmetic -> immune to any compiler math flags.
    if (a == 0.0f) return 0.0f;
    unsigned ua = __float_as_uint(a), ud = __float_as_uint(d);
    int      Ea = (int)((ua >> 23) & 0xFFu);
    int      Ed = (int)((ud >> 23) & 0xFFu);
    unsigned Ma = ua & 0x7FFFFFu;
    unsigned Md = ud & 0x7FFFFFu;
    if (Ea) { Ma |= 0x800000u; } else { int sh = __clz(Ma) - 8; Ma <<= sh; Ea = 1 - sh; }
    if (Ed) { Md |= 0x800000u; } else { int sh = __clz(Md) - 8; Md <<= sh; Ed = 1 - sh; }
    unsigned long long num = (unsigned long long)Ma << 26;
    unsigned long long q0  = num / Md;
    unsigned long long rem = num - q0 * Md;
    unsigned Q, rnd; bool sticky; int Eout;
    if (q0 >= (1ull << 26)) {
        Q = (unsigned)(q0 >> 3); rnd = (unsigned)(q0 >> 2) & 1u;
        sticky = ((q0 & 3ull) != 0) || (rem != 0); Eout = Ea - Ed + 127;
    } else {
        Q = (unsigned)(q0 >> 2); rnd = (unsigned)(q0 >> 1) & 1u;
        sticky = ((q0 & 1ull) != 0) || (rem != 0); Eout = Ea - Ed + 126;
    }
    if (rnd && (sticky || (Q & 1u))) ++Q;
    if (Q == (1u << 24)) { Q = 1u << 23; ++Eout; }
    if (Eout < 1)   return 0.0f;
    if (Eout > 254) Eout = 254;
    return __uint_as_float(((unsigned)Eout << 23) | (Q & 0x7FFFFFu));
}

__device__ __forceinline__ int np_bucket(float v, float mn, float inv) {
    float a  = v - mn;              // single IEEE sub
    float xn = a * inv;             // single IEEE mul (RN)
    asm volatile("" : "+v"(xn));    // forbid (a*inv)*127 reassociation
    float s  = xn * 127.0f;         // single IEEE mul (RN)
    s = fminf(fmaxf(s, 0.0f), 127.0f);
    return (int)s;                  // trunc == floor (s >= 0)
}

extern "C" __global__ __launch_bounds__(1024)
void MarkovTransition_50637664420500_kernel(const float* __restrict__ x,
                                            float* __restrict__ out)
{
    __shared__ unsigned int  cp[8192];    // 32 KiB: packed u16 counts / scratch
    __shared__ unsigned char wfirst[16];  // bucket of each wave's element 0
    __shared__ float         rs[128];     // row sums

    const int tid  = threadIdx.x;
    const int bid  = blockIdx.x;          // XCD swizzle: bid = b + 4*f
    const int b    = bid & 3, f = bid >> 2;
    const int w    = tid >> 6, lane = tid & 63;
    const float* xs = x + b * 65536 + f;

    // ---- Phase 1: wave-coalesced loads, element l = w*512 + k*64 + lane ----
    float v[8];
    #pragma unroll
    for (int k = 0; k < 8; ++k) v[k] = xs[(w * 512 + k * 64 + lane) * 8];

    float mn = v[0], mx = v[0];
    #pragma unroll
    for (int k = 1; k < 8; ++k) { mn = fminf(mn, v[k]); mx = fmaxf(mx, v[k]); }
    #pragma unroll
    for (int off = 32; off > 0; off >>= 1) {
        mn = fminf(mn, __shfl_xor(mn, off));
        mx = fmaxf(mx, __shfl_xor(mx, off));
    }
    if (lane == 0) { cp[w] = __float_as_uint(mn); cp[64 + w] = __float_as_uint(mx); }
    __syncthreads();
    if (tid < 64) {   // parallel merge of 16 wave partials
        float m0 = (lane < 16) ? __uint_as_float(cp[lane])      :  3.0e38f;
        float m1 = (lane < 16) ? __uint_as_float(cp[64 + lane]) : -3.0e38f;
        #pragma unroll
        for (int off = 8; off > 0; off >>= 1) {
            m0 = fminf(m0, __shfl_xor(m0, off));
            m1 = fmaxf(m1, __shfl_xor(m1, off));
        }
        if (lane == 0) { cp[128] = __float_as_uint(m0); cp[129] = __float_as_uint(m1); }
    }
    __syncthreads();
    const float x_min = __uint_as_float(cp[128]);
    const float inv   = ieee_div_rn(1.0f, fmaxf(__uint_as_float(cp[129]) - x_min, 1e-8f));
    __syncthreads();   // broadcasts consumed before cp is zeroed

    // ---- Phase 2: buckets (verified np chain) + publish wave-first buckets ----
    int bk[8];
    #pragma unroll
    for (int k = 0; k < 8; ++k) bk[k] = np_bucket(v[k], x_min, inv);
    if (lane == 0) wfirst[w] = (unsigned char)bk[0];
    #pragma unroll
    for (int i = 0; i < 8; ++i) cp[tid + i * 1024] = 0u;
    __syncthreads();

    // ---- Phase 3: histogram — successor via shfl_down; lane 63 patched
    // from lane 0 of next k (or next wave's first bucket via wfirst).
    // Packed u16 LDS atomics; per-cell max 8191 < 65536 -> no carry.
    #pragma unroll
    for (int k = 0; k < 8; ++k) {
        int bc0;
        if (k < 7) bc0 = __shfl(bk[k + 1], 0);
        else       bc0 = (w < 15) ? (int)wfirst[w + 1] : -1;
        int nb = __shfl_down(bk[k], 1);
        if (lane == 63) nb = bc0;
        if (nb >= 0) {   // excludes only the final element l = 8191
            const int cell = bk[k] * 128 + nb;
            atomicAdd(&cp[cell >> 1], 1u << ((cell & 1) << 4));
        }
    }
    __syncthreads();

    // ---- Phase 4: row sums — 8 threads/row, shuffle reduce ----
    {
        const int j = tid & 7;
        unsigned s = 0;
        #pragma unroll
        for (int i = 0; i < 8; ++i) {
            const unsigned u = cp[tid * 8 + i];
            s += (u & 0xFFFFu) + (u >> 16);
        }
        s += __shfl_xor(s, 1);
        s += __shfl_xor(s, 2);
        s += __shfl_xor(s, 4);
        if (j == 0) rs[tid >> 3] = fmaxf((float)s, 1e-8f);
    }
    __syncthreads();

    // ---- Phase 5: normalize + float4 stores (output series = b*8 + f) ----
    float4* P4 = (float4*)(out + (b * 8 + f) * 16384);
    #pragma unroll
    for (int i = 0; i < 4; ++i) {
        const int idx = tid + i * 1024;           // float4 index, 0..4095
        const unsigned u0 = cp[2 * idx];
        const unsigned u1 = cp[2 * idx + 1];
        const float r = rs[idx >> 5];             // row = (2*idx)>>6
        P4[idx] = make_float4((float)(u0 & 0xFFFFu) / r, (float)(u0 >> 16) / r,
                              (float)(u1 & 0xFFFFu) / r, (float)(u1 >> 16) / r);
    }
}

extern "C" void kernel_launch(void* const* d_in, const int* in_sizes, int n_in,
                              void* d_out, int out_size, void* d_ws, size_t ws_size,
                              hipStream_t stream) {
    const float* x = (const float*)d_in[0];
    float* out = (float*)d_out;
    MarkovTransition_50637664420500_kernel<<<32, 1024, 0, stream>>>(x, out);
}

// Round 28
// 14.298 us; speedup vs baseline: 1.8325x; 1.0078x over previous
//
#include <hip/hip_runtime.h>

// MarkovTransition: x (4, 8192, 8) fp32 -> P (4, 8, 128, 128) fp32.
// VERIFIED SEMANTICS (r23-r27, absmax 0.0): per-series (b,f) min/max;
// inv = RN(1/max(mx-mn,1e-8)); xn = (v-mn)*inv; s = xn*127; clip; floor.
// C[s,t] counts consecutive-pair transitions; P = C / max(rowsum, 1e-8).
//
// r28: critical-path thinning of the single-kernel structure (r26 proved
// multi-node splits cost ~4-6 us/node; r27 proved memory pattern is null).
//  - LDS count-zeroing overlapped with global-load latency (dedicated
//    minmax scratch instead of reusing cp -> one fewer barrier).
//  - rowsum fused into the histogram pass: rowsum[r] = #pairs starting in
//    r, accumulated by a parallel rsum atomic -> phase 4 eliminated.
//  - wave-boundary successor handled by lane 63 loading the next element
//    directly (L2-warm) -> wfirst array + its barrier eliminated.
// Barriers 6 -> 3. Counts/rowsums bit-identical -> absmax stays 0.0.

__device__ __forceinline__ float ieee_div_rn(float a, float d) {
    // Correctly-rounded (RNE) fp32 a/d for finite a >= 0, d > 0.
    // Pure integer arithmetic -> immune to any compiler math flags.
    if (a == 0.0f) return 0.0f;
    unsigned ua = __float_as_uint(a), ud = __float_as_uint(d);
    int      Ea = (int)((ua >> 23) & 0xFFu);
    int      Ed = (int)((ud >> 23) & 0xFFu);
    unsigned Ma = ua & 0x7FFFFFu;
    unsigned Md = ud & 0x7FFFFFu;
    if (Ea) { Ma |= 0x800000u; } else { int sh = __clz(Ma) - 8; Ma <<= sh; Ea = 1 - sh; }
    if (Ed) { Md |= 0x800000u; } else { int sh = __clz(Md) - 8; Md <<= sh; Ed = 1 - sh; }
    unsigned long long num = (unsigned long long)Ma << 26;
    unsigned long long q0  = num / Md;
    unsigned long long rem = num - q0 * Md;
    unsigned Q, rnd; bool sticky; int Eout;
    if (q0 >= (1ull << 26)) {
        Q = (unsigned)(q0 >> 3); rnd = (unsigned)(q0 >> 2) & 1u;
        sticky = ((q0 & 3ull) != 0) || (rem != 0); Eout = Ea - Ed + 127;
    } else {
        Q = (unsigned)(q0 >> 2); rnd = (unsigned)(q0 >> 1) & 1u;
        sticky = ((q0 & 1ull) != 0) || (rem != 0); Eout = Ea - Ed + 126;
    }
    if (rnd && (sticky || (Q & 1u))) ++Q;
    if (Q == (1u << 24)) { Q = 1u << 23; ++Eout; }
    if (Eout < 1)   return 0.0f;
    if (Eout > 254) Eout = 254;
    return __uint_as_float(((unsigned)Eout << 23) | (Q & 0x7FFFFFu));
}

__device__ __forceinline__ int np_bucket(float v, float mn, float inv) {
    float a  = v - mn;              // single IEEE sub
    float xn = a * inv;             // single IEEE mul (RN)
    asm volatile("" : "+v"(xn));    // forbid (a*inv)*127 reassociation
    float s  = xn * 127.0f;         // single IEEE mul (RN)
    s = fminf(fmaxf(s, 0.0f), 127.0f);
    return (int)s;                  // trunc == floor (s >= 0)
}

extern "C" __global__ __launch_bounds__(1024)
void MarkovTransition_50637664420500_kernel(const float* __restrict__ x,
                                            float* __restrict__ out)
{
    __shared__ unsigned int cp[8192];    // 32 KiB: packed u16 counts
    __shared__ unsigned int rsum[128];   // row sums (fused into histogram)
    __shared__ float smn[16], smx[16], sbc[2];

    const int tid  = threadIdx.x;
    const int bid  = blockIdx.x;         // XCD swizzle: bid = b + 4*f
    const int b    = bid & 3, f = bid >> 2;
    const int w    = tid >> 6, lane = tid & 63;
    const float* xs = x + b * 65536 + f;

    // ---- Phase 1: issue wave-coalesced loads (l = w*512 + k*64 + lane),
    // then zero LDS while the loads are in flight.
    float v[8];
    #pragma unroll
    for (int k = 0; k < 8; ++k) v[k] = xs[(w * 512 + k * 64 + lane) * 8];
    float vex = 0.0f;
    if (lane == 63 && w < 15) vex = xs[(w * 512 + 512) * 8];  // wave-boundary successor

    #pragma unroll
    for (int i = 0; i < 8; ++i) cp[tid + i * 1024] = 0u;
    if (tid < 128) rsum[tid] = 0u;

    // ---- min/max: per-thread, wave shuffle, publish to scratch ----
    float mn = v[0], mx = v[0];
    #pragma unroll
    for (int k = 1; k < 8; ++k) { mn = fminf(mn, v[k]); mx = fmaxf(mx, v[k]); }
    #pragma unroll
    for (int off = 32; off > 0; off >>= 1) {
        mn = fminf(mn, __shfl_xor(mn, off));
        mx = fmaxf(mx, __shfl_xor(mx, off));
    }
    if (lane == 0) { smn[w] = mn; smx[w] = mx; }
    __syncthreads();                                   // B1: zeros + partials
    if (tid < 64) {
        float m0 = (lane < 16) ? smn[lane] :  3.0e38f;
        float m1 = (lane < 16) ? smx[lane] : -3.0e38f;
        #pragma unroll
        for (int off = 8; off > 0; off >>= 1) {
            m0 = fminf(m0, __shfl_xor(m0, off));
            m1 = fmaxf(m1, __shfl_xor(m1, off));
        }
        if (lane == 0) { sbc[0] = m0; sbc[1] = m1; }
    }
    __syncthreads();                                   // B2: broadcast ready
    const float x_min = sbc[0];
    const float inv   = ieee_div_rn(1.0f, fmaxf(sbc[1] - x_min, 1e-8f));

    // ---- Phase 2: buckets (verified np chain) ----
    int bk[8];
    #pragma unroll
    for (int k = 0; k < 8; ++k) bk[k] = np_bucket(v[k], x_min, inv);
    const int bex = (lane == 63 && w < 15) ? np_bucket(vex, x_min, inv) : -1;

    // ---- Phase 3: histogram + fused rowsum (successors via shfl;
    // lane 63 of k<7 takes lane 0 of k+1; k==7 takes the directly-loaded
    // boundary bucket; w==15/k==7/lane==63 is l=8191 -> excluded).
    // Packed u16 LDS atomics; per-cell max 8191 < 65536 -> no carry.
    #pragma unroll
    for (int k = 0; k < 8; ++k) {
        const int fromNext = (k < 7) ? __shfl(bk[k + 1], 0) : 0;  // full-wave shfl
        int nb = __shfl_down(bk[k], 1);
        if (lane == 63) nb = (k < 7) ? fromNext : bex;
        if (nb >= 0) {
            const int cell = bk[k] * 128 + nb;
            atomicAdd(&cp[cell >> 1], 1u << ((cell & 1) << 4));
            atomicAdd(&rsum[bk[k]], 1u);               // rowsum, exact
        }
    }
    __syncthreads();                                   // B3: counts final

    // ---- Phase 4: normalize + float4 stores (output series = b*8 + f) ----
    float4* P4 = (float4*)(out + (b * 8 + f) * 16384);
    #pragma unroll
    for (int i = 0; i < 4; ++i) {
        const int idx = tid + i * 1024;                // float4 index 0..4095
        const unsigned u0 = cp[2 * idx];
        const unsigned u1 = cp[2 * idx + 1];
        const float r = fmaxf((float)rsum[idx >> 5], 1e-8f);   // row = idx>>5
        P4[idx] = make_float4((float)(u0 & 0xFFFFu) / r, (float)(u0 >> 16) / r,
                              (float)(u1 & 0xFFFFu) / r, (float)(u1 >> 16) / r);
    }
}

extern "C" void kernel_launch(void* const* d_in, const int* in_sizes, int n_in,
                              void* d_out, int out_size, void* d_ws, size_t ws_size,
                              hipStream_t stream) {
    const float* x = (const float*)d_in[0];
    float* out = (float*)d_out;
    MarkovTransition_50637664420500_kernel<<<32, 1024, 0, stream>>>(x, out);
}